// Round 9
// baseline (242.715 us; speedup 1.0000x reference)
//
#include <hip/hip_runtime.h>
#include <math.h>

// MultiHeadBigBirdAttention: B=2, S=2048, E=1024, H=8, DH=128
// Pipeline (bf16 MFMA 16x16x32):
//   1. prep: fused {q,k,v fp32->bf16} + {W* fp32 [K][N] -> bf16 W^T [N][K]}
//   2. gemm_qkv (grid 32x8x3): projections -> Qh/Kh [B,H,S,DH], Vt [B,H,DH,S]
//   3. flash_k: static-max flash v9 -> ctx bf16
//   4. gemm_out (grid 64x8): ctx @ Wo^T + bo -> d_out fp32, BM=64 tile
//
// MFMA layouts (verified learn_hip m89/m91/m120):
//   C/D: col = lane&15, row = (lane>>4)*4 + reg
//   A:   m   = lane&15, k   = (lane>>4)*8 + j
//   B:   n   = lane&15, k   = (lane>>4)*8 + j
//
// R17: flash v9 — 8-wave blocks + V-in-registers.
// R13/R16 counters: flash latency-bound at 2 waves/SIMD (512 blk x 4 waves
// is a chip-wide wave cap; halving LDS reads in R13 gave only -6%).
// This round keeps 512 blocks + t/(31-t) pairing but runs 512 threads:
// wave (r=w>>1: 16 rows, kh=w&1: 32 keys). Key-split means each wave needs
// only one 16B chunk per V row -> V leaves LDS entirely: 8 bf16x8 per wave
// loaded global->reg at iter top (L2-resident, bh%8 XCD-local), consumed
// at PV ~800cyc later. LDS = K dbuf 32K + P 10K = 43KB -> 2 blocks/CU x 8
// waves = 4 waves/SIMD (2x R13 TLP). launch_bounds(512,4) caps VGPR at 128
// vs ~115 demand (NOT R14's trap: cap > demand). K staging/swizzles/diag/
// combine all carried from R13.

typedef __bf16 bf16_t;
typedef __bf16 bf16x8 __attribute__((ext_vector_type(8)));
typedef float f32x4 __attribute__((ext_vector_type(4)));

#define MFMA16(a, b, c) __builtin_amdgcn_mfma_f32_16x16x32_bf16(a, b, c, 0, 0, 0)

// ---------------------------------------------------------------------------
// prep: blocks 0..6143 convert q/k/v fp32->bf16 (8 elems/thread);
//       blocks 6144..10239 transpose the 4 weight matrices to bf16 W^T.
// ---------------------------------------------------------------------------
__global__ __launch_bounds__(256) void prep(const float* q, const float* k,
                                            const float* v, bf16_t* qb,
                                            bf16_t* kb, bf16_t* vb,
                                            const float* W0, const float* W1,
                                            const float* W2, const float* W3,
                                            bf16_t* Wt) {
  const int bid = blockIdx.x, tid = threadIdx.x;
  if (bid < 6144) {
    const int z = bid >> 11, chunk = bid & 2047;
    const float* x = (z == 0) ? q : (z == 1) ? k : v;
    bf16_t* y = (z == 0) ? qb : (z == 1) ? kb : vb;
    size_t i = ((size_t)chunk * 256 + tid) * 8;
    float4 a = *(const float4*)(x + i);
    float4 b = *(const float4*)(x + i + 4);
    bf16x8 o = {(bf16_t)a.x, (bf16_t)a.y, (bf16_t)a.z, (bf16_t)a.w,
                (bf16_t)b.x, (bf16_t)b.y, (bf16_t)b.z, (bf16_t)b.w};
    *(bf16x8*)(y + i) = o;
  } else {
    __shared__ float t[32][33];
    const int b2 = bid - 6144;
    const int wz = b2 >> 10, t2 = b2 & 1023;
    const float* W = (wz == 0) ? W0 : (wz == 1) ? W1 : (wz == 2) ? W2 : W3;
    bf16_t* o = Wt + (size_t)wz * 1024 * 1024;
    const int n0 = (t2 & 31) * 32, k0 = (t2 >> 5) * 32;
    const int tx = tid & 31, ty = tid >> 5;
#pragma unroll
    for (int i = 0; i < 4; i++)
      t[ty + 8 * i][tx] = W[(size_t)(k0 + ty + 8 * i) * 1024 + n0 + tx];
    __syncthreads();
#pragma unroll
    for (int i = 0; i < 4; i++)
      o[(size_t)(n0 + ty + 8 * i) * 1024 + k0 + tx] = (bf16_t)t[tx][ty + 8 * i];
  }
}

// ---------------------------------------------------------------------------
// gemm_qkv: 128x128 tile, BK=64, LDS double-buffered, register-staged
// pipeline (R8 skeleton, proven). Grid (bm=32, bn=8, z=3) -> XCD = bm%8;
// per-XCD L2 working set = 4 A-tiles (1MB) + W^T (2MB).
// ---------------------------------------------------------------------------
__global__ __launch_bounds__(256) void gemm_qkv(
    const bf16_t* qb, const bf16_t* kb, const bf16_t* vb, const bf16_t* Wt,
    const float* b0, const float* b1, const float* b2, bf16_t* Qh, bf16_t* Kh,
    bf16_t* Vt) {
  __shared__ bf16_t As[2][128 * 64];
  __shared__ bf16_t Bs[2][128 * 64];
  const int tid = threadIdx.x, w = tid >> 6, lane = tid & 63;
  const int bm = blockIdx.x, bn = blockIdx.y;  // XCD = bm%8
  const int wr = w >> 1, wc = w & 1, q4 = lane >> 4, lo = lane & 15;
  const int z = blockIdx.z;
  const bf16_t* A = (z == 0) ? qb : (z == 1) ? kb : vb;
  const bf16_t* Bt = Wt + (size_t)z * 1024 * 1024;
  const float* bias = (z == 0) ? b0 : (z == 1) ? b1 : b2;

  f32x4 acc[4][4];
#pragma unroll
  for (int m = 0; m < 4; m++)
#pragma unroll
    for (int n = 0; n < 4; n++) acc[m][n] = (f32x4){0.f, 0.f, 0.f, 0.f};

  const int r2 = tid >> 1;         // 0..127
  const int cb = (tid & 1) * 4;    // chunk base 0 / 4
  const bf16_t* Arow = A + (size_t)(bm * 128 + r2) * 1024;
  const bf16_t* Brow = Bt + (size_t)(bn * 128 + r2) * 1024;

  bf16x8 ar[4], br[4];
  auto loadAB = [&](int k0) {
#pragma unroll
    for (int i = 0; i < 4; i++) {
      ar[i] = *(const bf16x8*)(Arow + k0 + (cb + i) * 8);
      br[i] = *(const bf16x8*)(Brow + k0 + (cb + i) * 8);
    }
  };

  loadAB(0);
  for (int k = 0; k < 16; k++) {
    const int cur = k & 1;
    // deposit tile k (waits only on its own global loads)
#pragma unroll
    for (int i = 0; i < 4; i++) {
      *(bf16x8*)&As[cur][r2 * 64 + (((cb + i) ^ (r2 & 7)) * 8)] = ar[i];
      *(bf16x8*)&Bs[cur][r2 * 64 + (((cb + i) ^ (r2 & 7)) * 8)] = br[i];
    }
    // prefetch tile k+1 into private regs (in flight through barrier+compute)
    if (k < 15) loadAB((k + 1) * 64);
    __syncthreads();

#pragma unroll
    for (int kc = 0; kc < 2; kc++) {
      bf16x8 af[4], bfr[4];
#pragma unroll
      for (int m = 0; m < 4; m++) {
        int rr = wr * 64 + m * 16 + lo;
        af[m] = *(const bf16x8*)&As[cur][rr * 64 + (((kc * 4 + q4) ^ (rr & 7)) * 8)];
      }
#pragma unroll
      for (int n = 0; n < 4; n++) {
        int rr = wc * 64 + n * 16 + lo;
        bfr[n] = *(const bf16x8*)&Bs[cur][rr * 64 + (((kc * 4 + q4) ^ (rr & 7)) * 8)];
      }
#pragma unroll
      for (int m = 0; m < 4; m++)
#pragma unroll
        for (int n = 0; n < 4; n++)
          acc[m][n] = MFMA16(af[m], bfr[n], acc[m][n]);
    }
    // no trailing barrier: dbuf + top-of-iter deposit make it safe
  }

#pragma unroll
  for (int m = 0; m < 4; m++) {
#pragma unroll
    for (int n = 0; n < 4; n++) {
      int rowg0 = bm * 128 + wr * 64 + m * 16 + q4 * 4;
      int colg = bn * 128 + wc * 64 + n * 16 + lo;
      float bv = bias[colg];
#pragma unroll
      for (int rg = 0; rg < 4; rg++) {
        float val = acc[m][n][rg] + bv;
        int row = rowg0 + rg;
        int b = row >> 11, s = row & 2047;  // S=2048
        int h = colg >> 7, d = colg & 127;  // DH=128
        if (z == 0)
          Qh[(((size_t)(b * 8 + h)) * 2048 + s) * 128 + d] = (bf16_t)val;
        else if (z == 1)
          Kh[(((size_t)(b * 8 + h)) * 2048 + s) * 128 + d] = (bf16_t)val;
        else
          Vt[(((size_t)(b * 8 + h)) * 128 + d) * 2048 + s] = (bf16_t)val;
      }
    }
  }
}

// ---------------------------------------------------------------------------
// gemm_out: BM=64 x BN=128 tile, BK=64. Grid (64, 8) = 512 blocks = 2/CU.
// 4 waves as 2x2: wave (wr,wc) computes rows wr*32..+31 x cols wc*64..+63.
// Same reg-staged dbuf skeleton and XOR-swizzle family as gemm_qkv.
// ---------------------------------------------------------------------------
__global__ __launch_bounds__(256) void gemm_out(const bf16_t* ctx,
                                                const bf16_t* Wt3,
                                                const float* bo, float* Of32) {
  __shared__ bf16_t As[2][64 * 64];
  __shared__ bf16_t Bs[2][128 * 64];
  const int tid = threadIdx.x, w = tid >> 6, lane = tid & 63;
  const int bm = blockIdx.x, bn = blockIdx.y;  // XCD = bm%8
  const int wr = w >> 1, wc = w & 1, q4 = lane >> 4, lo = lane & 15;

  f32x4 acc[2][4];
#pragma unroll
  for (int m = 0; m < 2; m++)
#pragma unroll
    for (int n = 0; n < 4; n++) acc[m][n] = (f32x4){0.f, 0.f, 0.f, 0.f};

  const int r2a = tid >> 2;        // 0..63
  const int cba = (tid & 3) * 2;   // chunk base 0/2/4/6
  const int r2b = tid >> 1;        // 0..127
  const int cbb = (tid & 1) * 4;   // chunk base 0/4
  const bf16_t* Arow = ctx + (size_t)(bm * 64 + r2a) * 1024;
  const bf16_t* Brow = Wt3 + (size_t)(bn * 128 + r2b) * 1024;

  bf16x8 ar[2], br[4];
  auto loadAB = [&](int k0) {
#pragma unroll
    for (int i = 0; i < 2; i++)
      ar[i] = *(const bf16x8*)(Arow + k0 + (cba + i) * 8);
#pragma unroll
    for (int i = 0; i < 4; i++)
      br[i] = *(const bf16x8*)(Brow + k0 + (cbb + i) * 8);
  };

  loadAB(0);
  for (int k = 0; k < 16; k++) {
    const int cur = k & 1;
#pragma unroll
    for (int i = 0; i < 2; i++)
      *(bf16x8*)&As[cur][r2a * 64 + (((cba + i) ^ (r2a & 7)) * 8)] = ar[i];
#pragma unroll
    for (int i = 0; i < 4; i++)
      *(bf16x8*)&Bs[cur][r2b * 64 + (((cbb + i) ^ (r2b & 7)) * 8)] = br[i];
    if (k < 15) loadAB((k + 1) * 64);
    __syncthreads();

#pragma unroll
    for (int kc = 0; kc < 2; kc++) {
      bf16x8 af[2], bfr[4];
#pragma unroll
      for (int m = 0; m < 2; m++) {
        int rr = wr * 32 + m * 16 + lo;
        af[m] = *(const bf16x8*)&As[cur][rr * 64 + (((kc * 4 + q4) ^ (rr & 7)) * 8)];
      }
#pragma unroll
      for (int n = 0; n < 4; n++) {
        int rr = wc * 64 + n * 16 + lo;
        bfr[n] = *(const bf16x8*)&Bs[cur][rr * 64 + (((kc * 4 + q4) ^ (rr & 7)) * 8)];
      }
#pragma unroll
      for (int m = 0; m < 2; m++)
#pragma unroll
        for (int n = 0; n < 4; n++)
          acc[m][n] = MFMA16(af[m], bfr[n], acc[m][n]);
    }
  }

#pragma unroll
  for (int m = 0; m < 2; m++) {
#pragma unroll
    for (int n = 0; n < 4; n++) {
      int rowg0 = bm * 64 + wr * 32 + m * 16 + q4 * 4;
      int colg = bn * 128 + wc * 64 + n * 16 + lo;
      float bv = bo[colg];
#pragma unroll
      for (int rg = 0; rg < 4; rg++)
        Of32[(size_t)(rowg0 + rg) * 1024 + colg] = acc[m][n][rg] + bv;
    }
  }
}

// ---------------------------------------------------------------------------
// Flash attention v9: 512 blocks (t/(31-t) pairing preserved) x 512 threads.
// Wave (r=w>>1, kh=w&1) owns rows r*16..+15 x keys kh*32..+31 of the 64-row
// Q tile. K reg-staged dbuf LDS (R8 skeleton); V direct global->reg (each
// wave needs only chunk q4 of key-half kh per V row: 8 bf16x8). P wave-
// private [16][40]. LDS 43KB -> 2 blocks/CU = 4 waves/SIMD. Key-half
// partials combined once at end via dead K-dbuf arena.
// ---------------------------------------------------------------------------
__global__ __launch_bounds__(512, 4) void flash_k(const bf16_t* Qh,
                                                  const bf16_t* Kh,
                                                  const bf16_t* Vt, bf16_t* ctx,
                                                  const int* causal_p) {
  __shared__ bf16_t sm[16384 + 8 * 640];  // K dbuf 32KB + P 10KB
  const int tid = threadIdx.x, w = tid >> 6, lane = tid & 63;
  const int q4 = lane >> 4, lo = lane & 15;
  const int r = w >> 1, kh = w & 1;  // row-group (16 rows), key-half (32 keys)
  const int n0 = blockIdx.x;
  const int u = n0 & 255, hi = n0 >> 8;
  const int bh = u & 15, p0 = u >> 4;
  const int t = hi ? (31 - p0) : p0;
  const int causal = *causal_p;
  const int kmax = causal ? t : 31;

  bf16_t* Ps = sm + 16384 + w * 640;  // [16 rows][40]

  // Q fragments: rows t*64 + r*16 + lo, dh chunk ks*32 + q4*8.
  bf16x8 aq[4];
  {
    const bf16_t* qa =
        Qh + ((size_t)bh * 2048 + t * 64 + r * 16 + lo) * 128;
#pragma unroll
    for (int ks = 0; ks < 4; ks++)
      aq[ks] = *(const bf16x8*)(qa + ks * 32 + q4 * 8);
  }

  const bf16_t* Kbase = Kh + (size_t)bh * 2048 * 128;
  // V B-fragment base: row d = n*16+lo, keys kt*64 + kh*32 + q4*8..+7.
  const bf16_t* Vb = Vt + ((size_t)bh * 128 + lo) * 2048 + kh * 32 + q4 * 8;
  const int kr = tid >> 3, kc = (tid & 7) * 2;  // K staging: 2 chunks/thread

  bf16x8 kreg[2], vreg[8];
  auto loadK = [&](int kt) {
    const bf16_t* kp = Kbase + (size_t)(kt * 64 + kr) * 128;
#pragma unroll
    for (int i = 0; i < 2; i++) kreg[i] = *(const bf16x8*)(kp + (kc + i) * 8);
  };
  auto loadV = [&](int kt) {
#pragma unroll
    for (int n = 0; n < 8; n++)
      vreg[n] = *(const bf16x8*)(Vb + (size_t)n * (16 * 2048) + kt * 64);
  };

  f32x4 acc[8], lacc;
#pragma unroll
  for (int i = 0; i < 8; i++) acc[i] = (f32x4){0.f, 0.f, 0.f, 0.f};
  lacc = (f32x4){0.f, 0.f, 0.f, 0.f};

  const bf16_t one = (bf16_t)1.0f;
  const bf16x8 vone = {one, one, one, one, one, one, one, one};
  const float sc2 = 0.08838834764831845f * 1.44269504088896f;

  loadK(0);
  for (int kt = 0; kt <= kmax; ++kt) {
    bf16_t* Kd = sm + (kt & 1) * 8192;
    // deposit K tile kt (waits only on its own global loads)
#pragma unroll
    for (int i = 0; i < 2; i++)
      *(bf16x8*)&Kd[kr * 128 + (((kc + i) ^ (kr & 7)) * 8)] = kreg[i];
    if (kt < kmax) loadK(kt + 1);  // in flight through barrier+compute
    loadV(kt);                     // consumed at PV (~QK^T+softmax of cover)
    __syncthreads();

    // ---- QK^T: [16 rows x 32 keys] per wave ----
    f32x4 sa[2];
#pragma unroll
    for (int nt = 0; nt < 2; nt++) sa[nt] = (f32x4){0.f, 0.f, 0.f, 0.f};
#pragma unroll
    for (int ks = 0; ks < 4; ks++) {
#pragma unroll
      for (int nt = 0; nt < 2; nt++) {
        int key = kh * 32 + nt * 16 + lo;
        bf16x8 bk =
            *(const bf16x8*)&Kd[key * 128 + (((ks * 4 + q4) ^ (key & 7)) * 8)];
        sa[nt] = MFMA16(aq[ks], bk, sa[nt]);
      }
    }

    // ---- softmax numerator -> wave-private P [16 rows x 32 keys] ----
    const bool diag = causal && (kt == t);
#pragma unroll
    for (int nt = 0; nt < 2; nt++) {
      int keyrel = kh * 32 + nt * 16 + lo;  // within 64-key tile
#pragma unroll
      for (int rg = 0; rg < 4; rg++) {
        int rowrel = r * 16 + q4 * 4 + rg;
        float pv = exp2f(sa[nt][rg] * sc2);
        if (diag && keyrel > rowrel) pv = 0.f;
        Ps[(q4 * 4 + rg) * 40 + nt * 16 + lo] = (bf16_t)pv;
      }
    }

    // ---- P fragment (K=32 = wave's whole key-half), row-sum, PV ----
    bf16x8 ap = *(const bf16x8*)&Ps[lo * 40 + q4 * 8];
    lacc = MFMA16(ap, vone, lacc);
#pragma unroll
    for (int n = 0; n < 8; n++) acc[n] = MFMA16(ap, vreg[n], acc[n]);
  }

  // ---- combine key-half partials (once per block) ----
  __syncthreads();  // K dbuf now dead; all Ps reads done
  float* farena = (float*)sm;  // 8192 floats = 32KB (K dbuf region)
  if (kh == 1) {
    int base = r * 2048 + lane * 32;
#pragma unroll
    for (int n = 0; n < 8; n++)
      *(f32x4*)&farena[base + ((n ^ (lane & 7)) & 7) * 4] = acc[n];
    float* lp = (float*)(sm + 16384 + w * 640);
    *(f32x4*)&lp[lane * 4] = lacc;
  }
  __syncthreads();
  if (kh == 0) {
    int base = r * 2048 + lane * 32;
    float* lp = (float*)(sm + 16384 + (w + 1) * 640);
    lacc += *(const f32x4*)&lp[lane * 4];
#pragma unroll
    for (int n = 0; n < 8; n++)
      acc[n] += *(const f32x4*)&farena[base + ((n ^ (lane & 7)) & 7) * 4];
    int b = bh >> 3, h = bh & 7;
#pragma unroll
    for (int rg = 0; rg < 4; rg++) {
      float inv = 1.f / lacc[rg];
      int row = b * 2048 + t * 64 + r * 16 + q4 * 4 + rg;
#pragma unroll
      for (int n = 0; n < 8; n++)
        ctx[(size_t)row * 1024 + h * 128 + n * 16 + lo] =
            (bf16_t)(acc[n][rg] * inv);
    }
  }
}

// ---------------------------------------------------------------------------
extern "C" void kernel_launch(void* const* d_in, const int* in_sizes, int n_in,
                              void* d_out, int out_size, void* d_ws,
                              size_t ws_size, hipStream_t stream) {
  const float* q = (const float*)d_in[0];
  const float* k = (const float*)d_in[1];
  const float* v = (const float*)d_in[2];
  const float* Wq = (const float*)d_in[3];
  const float* bq = (const float*)d_in[4];
  const float* Wk = (const float*)d_in[5];
  const float* bk = (const float*)d_in[6];
  const float* Wv = (const float*)d_in[7];
  const float* bv = (const float*)d_in[8];
  const float* Wo = (const float*)d_in[9];
  const float* bo = (const float*)d_in[10];
  const int* isc = (const int*)d_in[11];

  char* ws = (char*)d_ws;
  bf16_t* Wt = (bf16_t*)ws;                     // 8MB: W^T bf16 x4
  bf16_t* qb = (bf16_t*)(ws + (8ull << 20));    // 8MB
  bf16_t* kb = (bf16_t*)(ws + (16ull << 20));   // 8MB
  bf16_t* vb = (bf16_t*)(ws + (24ull << 20));   // 8MB
  bf16_t* Qh = (bf16_t*)(ws + (32ull << 20));   // 8MB [B,H,S,DH]
  bf16_t* Kh = (bf16_t*)(ws + (40ull << 20));   // 8MB [B,H,S,DH]
  bf16_t* Vt = (bf16_t*)(ws + (48ull << 20));   // 8MB [B,H,DH,S]
  bf16_t* ctx = (bf16_t*)(ws + (8ull << 20));   // reuse qb

  prep<<<dim3(10240), 256, 0, stream>>>(q, k, v, qb, kb, vb, Wq, Wk, Wv, Wo, Wt);

  gemm_qkv<<<dim3(32, 8, 3), 256, 0, stream>>>(qb, kb, vb, Wt, bq, bk, bv, Qh,
                                               Kh, Vt);

  flash_k<<<dim3(512), 512, 0, stream>>>(Qh, Kh, Vt, ctx, isc);

  gemm_out<<<dim3(64, 8), 256, 0, stream>>>(ctx, Wt + 3ull * 1024 * 1024, bo,
                                            (float*)d_out);
}